// Round 11
// baseline (865.810 us; speedup 1.0000x reference)
//
#include <hip/hip_runtime.h>
#include <cstdint>

#define TT 24

typedef _Float16 half8 __attribute__((ext_vector_type(8)));
typedef float f32x4 __attribute__((ext_vector_type(4)));

static __device__ __forceinline__ float fsig(float x){
  float e = __builtin_amdgcn_exp2f(-1.44269504f*x);
  return __builtin_amdgcn_rcpf(1.0f + e);
}
static __device__ __forceinline__ float ftanh(float x){
  float e = __builtin_amdgcn_exp2f(-2.88539008f*x);
  return fmaf(2.0f, __builtin_amdgcn_rcpf(1.0f + e), -1.0f);
}
static __device__ __forceinline__ float lrelu(float x){ return x > 0.f ? x : 0.2f*x; }

static __device__ __forceinline__ int swzh(int b){ return b ^ (((b>>7)&7)<<4); }
static __device__ __forceinline__ float h2f_lo(unsigned u){
  union { unsigned short s; _Float16 f; } c; c.s = (unsigned short)(u & 0xFFFF); return (float)c.f;
}
static __device__ __forceinline__ float h2f_hi(unsigned u){
  union { unsigned short s; _Float16 f; } c; c.s = (unsigned short)(u >> 16); return (float)c.f;
}

// ---------------- prep: B-fragment build (fp16) + linwT + cE ----------------
// Bf[((mat*32 + c*16 + tau)*512) + l*8 + j] = fp16( W[k=32c+8*(l>>4)+j][col=16*tau+(l&15)] )
// where W[k][col] = wsrc[col*64+k]; mat 0=w_hh0, 1=w_ih1, 2=w_hh1. col = gate*64+jp.
__global__ void kPrep(const float* __restrict__ w_hh0, const float* __restrict__ w_ih1,
                      const float* __restrict__ w_hh1, const float* __restrict__ lin_w,
                      const float* __restrict__ lin_edge_w, const float* __restrict__ att_edge,
                      unsigned short* __restrict__ Bf,
                      float* __restrict__ linwT, float* __restrict__ cE)
{
  int gid = blockIdx.x*256 + threadIdx.x;
  if (gid < 49152){
    int mat = gid / 16384;
    int r = gid - mat*16384;
    int c = r>>13, nt = (r>>9)&15, l = (r>>3)&63, j = r&7;
    int k = c*32 + (l>>4)*8 + j;
    int col = nt*16 + (l&15);
    const float* wsrc = (mat==0) ? w_hh0 : (mat==1 ? w_ih1 : w_hh1);
    float v = wsrc[col*64 + k];
    union { _Float16 f; unsigned short u; } cv;
    cv.f = (_Float16)v;
    Bf[gid] = cv.u;
  }
  int g2 = gid - 49152;
  if (g2 >= 0 && g2 < 72*128){
    int k = g2 >> 7, ch = g2 & 127;
    linwT[g2] = lin_w[ch*72 + k];
  }
  if (gid >= 58368 && gid < 58372){
    int h = gid - 58368;
    float s = 0.f;
    for (int c=0;c<32;c++) s += lin_edge_w[h*32+c]*att_edge[h*32+c];
    cE[h] = s;
  }
}

// ---------------- fused 2-layer LSTM via fp16 MFMA, weights in VGPRs ----------------
// 32 nodes/block, 256 threads = 4 waves. Wave wq owns taus nt*4+wq (all 4 gates).
// Each wave preloads its 24 B-fragments (3 mats x 2c x 4nt = 96 VGPR) -> ZERO weight
// reads in the t-loop (R9 lesson: B-fragment ds_reads were 2/3 of LDS traffic).
// LDS ~11 KB; VGPR ~190 -> 2 blocks/CU -> cross-block phase overlap.
// Nonlin in registers (gate-major). 3 barriers/step. h fp16 in LDS, XOR-swizzled.
// A/B k-slot convention (verified R6-R9): k = c*32 + (lane>>4)*8 + j both operands.
// C/D: col=lane&15, row=(lane>>4)*4+reg (m89).
__global__ __launch_bounds__(256) void kAB(const float* __restrict__ x,
    const unsigned short* __restrict__ Bf,
    const float* __restrict__ w_ih0, const float* __restrict__ b_ih0, const float* __restrict__ b_hh0,
    const float* __restrict__ b_ih1, const float* __restrict__ b_hh1,
    float* __restrict__ h2last, int N)
{
  __shared__ __align__(16) unsigned short sH1[2048];   // [32 node][64 jp] fp16, swizzled
  __shared__ __align__(16) unsigned short sH2[2048];
  __shared__ float sX[32*25];                          // padded stride 25
  const int tid = threadIdx.x;
  const int wq = tid>>6, l = tid&63;
  const int lr = l&15, lg = l>>4;
  const int nb = blockIdx.x*32;

  for (int i=tid;i<768;i+=256){
    int m = i/24, tt = i - m*24;
    int n = nb + m;
    sX[m*25+tt] = (n<N) ? x[(size_t)n*32 + 8 + tt] : 0.f;
  }
  for (int i=tid;i<2048;i+=256){ sH1[i]=0; sH2[i]=0; }

  // per-wave weight fragments -> VGPR (compile-time indexed after unroll)
  half8 w0[2][4], w1i[2][4], w1h[2][4];
  #pragma unroll
  for (int c=0;c<2;c++){
    #pragma unroll
    for (int nt=0;nt<4;nt++){
      w0 [c][nt] = *(const half8*)&Bf[(( 0 + c*16 + nt*4 + wq)<<9) + l*8];
      w1i[c][nt] = *(const half8*)&Bf[((32 + c*16 + nt*4 + wq)<<9) + l*8];
      w1h[c][nt] = *(const half8*)&Bf[((64 + c*16 + nt*4 + wq)<<9) + l*8];
    }
  }

  float wih[4], bb0[4], bb1[4];
  #pragma unroll
  for (int nt=0;nt<4;nt++){
    int col = nt*64 + wq*16 + lr;
    wih[nt] = w_ih0[col];
    bb0[nt] = b_ih0[col] + b_hh0[col];
    bb1[nt] = b_ih1[col] + b_hh1[col];
  }
  float cc0[8], cc1[8];
  #pragma unroll
  for (int i=0;i<8;i++){ cc0[i]=0.f; cc1[i]=0.f; }
  __syncthreads();

  const char* h1B = (const char*)sH1;
  const char* h2B = (const char*)sH2;

  for (int t=0;t<TT;t++){
    // ========== GEMM0: preact0 = h1(t-1)*W0 + x_t*wih + b  (acc in regs) ==========
    f32x4 acc[2][4];
    #pragma unroll
    for (int mt=0;mt<2;mt++){
      #pragma unroll
      for (int r=0;r<4;r++){
        float xv = sX[(mt*16 + lg*4 + r)*25 + t];
        #pragma unroll
        for (int nt=0;nt<4;nt++) acc[mt][nt][r] = fmaf(xv, wih[nt], bb0[nt]);
      }
    }
    #pragma unroll
    for (int c=0;c<2;c++){
      half8 a[2];
      #pragma unroll
      for (int mt=0;mt<2;mt++)
        a[mt] = *(const half8*)(h1B + swzh((mt*16+lr)*128 + c*64 + lg*16));
      #pragma unroll
      for (int nt=0;nt<4;nt++){
        #pragma unroll
        for (int mt=0;mt<2;mt++)
          acc[mt][nt] = __builtin_amdgcn_mfma_f32_16x16x32_f16(a[mt], w0[c][nt], acc[mt][nt], 0,0,0);
      }
    }
    __syncthreads();   // B1: all waves done reading sH1(t-1)
    // ========== nonlin0 (registers) -> write h1(t) fp16 ==========
    #pragma unroll
    for (int mt=0;mt<2;mt++){
      #pragma unroll
      for (int r=0;r<4;r++){
        int idx = mt*4+r, nd = mt*16 + lg*4 + r;
        float ig = fsig(acc[mt][0][r]), fg = fsig(acc[mt][1][r]);
        float gg = ftanh(acc[mt][2][r]), og = fsig(acc[mt][3][r]);
        cc0[idx] = fg*cc0[idx] + ig*gg;
        float h = og*ftanh(cc0[idx]);
        union { _Float16 f; unsigned short u; } cv; cv.f = (_Float16)h;
        *(unsigned short*)((char*)sH1 + swzh(nd*128 + (wq*16+lr)*2)) = cv.u;
      }
    }
    __syncthreads();   // B2: h1(t) visible
    // ========== GEMM1: preact1 = [h1(t);h2(t-1)] * [Wih1;Whh1] + b ==========
    #pragma unroll
    for (int mt=0;mt<2;mt++)
      #pragma unroll
      for (int nt=0;nt<4;nt++)
        #pragma unroll
        for (int r=0;r<4;r++) acc[mt][nt][r] = bb1[nt];
    #pragma unroll
    for (int c4=0;c4<4;c4++){
      const char* srcA = (c4<2) ? h1B : h2B;
      const int cc = c4&1;
      half8 a[2];
      #pragma unroll
      for (int mt=0;mt<2;mt++)
        a[mt] = *(const half8*)(srcA + swzh((mt*16+lr)*128 + cc*64 + lg*16));
      #pragma unroll
      for (int nt=0;nt<4;nt++){
        half8 b = (c4<2) ? w1i[cc][nt] : w1h[cc][nt];
        #pragma unroll
        for (int mt=0;mt<2;mt++)
          acc[mt][nt] = __builtin_amdgcn_mfma_f32_16x16x32_f16(a[mt], b, acc[mt][nt], 0,0,0);
      }
    }
    __syncthreads();   // B3: all waves done reading sH2(t-1)
    // ========== nonlin1 (registers) -> write h2(t) fp16; fp32 out at t=23 ==========
    #pragma unroll
    for (int mt=0;mt<2;mt++){
      #pragma unroll
      for (int r=0;r<4;r++){
        int idx = mt*4+r, nd = mt*16 + lg*4 + r;
        float ig = fsig(acc[mt][0][r]), fg = fsig(acc[mt][1][r]);
        float gg = ftanh(acc[mt][2][r]), og = fsig(acc[mt][3][r]);
        cc1[idx] = fg*cc1[idx] + ig*gg;
        float h = og*ftanh(cc1[idx]);
        union { _Float16 f; unsigned short u; } cv; cv.f = (_Float16)h;
        *(unsigned short*)((char*)sH2 + swzh(nd*128 + (wq*16+lr)*2)) = cv.u;
        if (t == TT-1){
          int n = nb + nd;
          if (n < N) h2last[(size_t)n*64 + wq*16 + lr] = h;
        }
      }
    }
    // no 4th barrier: sH2(t) writes vs G1(t+1) reads separated by B1+B2 of t+1;
    // G0(t+1) touches only sH1.
  }
}

// ---------------- GAT linear + attention coefficients ----------------
// xl stored PACKED fp16: ushort at n*128 + (ch&63)*2 + (ch>>6)  (pair = one u32/lane in kAgg)
__global__ __launch_bounds__(256) void kXL(const float* __restrict__ h2last, const float* __restrict__ x,
    const float* __restrict__ linwT, const float* __restrict__ att_src, const float* __restrict__ att_dst,
    unsigned short* __restrict__ xlh, float* __restrict__ a_src, float* __restrict__ a_dst, int N)
{
  __shared__ float sLW[72*128];
  __shared__ float sC[16*72];
  const int tid = threadIdx.x;
  const int nb0 = blockIdx.x * 16;
  for (int i = tid*4; i < 9216; i += 1024)
    *(float4*)&sLW[i] = *(const float4*)&linwT[i];
  for (int i = tid; i < 16*64; i += 256){
    int m = i >> 6, k = i & 63; int n = nb0 + m;
    sC[m*72 + k] = (n < N) ? h2last[(size_t)n*64 + k] : 0.f;
  }
  if (tid < 128){
    int m = tid >> 3, j = tid & 7; int n = nb0 + m;
    sC[m*72 + 64 + j] = (n < N) ? x[(size_t)n*32 + j] : 0.f;
  }
  __syncthreads();
  const int ch = tid & 127, half = tid >> 7;
  float acc[8];
  #pragma unroll
  for (int m=0;m<8;m++) acc[m]=0.f;
  for (int k=0;k<72;k++){
    float w = sLW[k*128 + ch];
    #pragma unroll
    for (int m=0;m<8;m++) acc[m] += w * sC[(half*8+m)*72 + k];
  }
  float aS = att_src[ch], aD = att_dst[ch];
  int h = ch >> 5;
  #pragma unroll
  for (int m=0;m<8;m++){
    int n = nb0 + half*8 + m;
    float v = acc[m];
    float ps = v*aS, pd = v*aD;
    #pragma unroll
    for (int d=1; d<32; d<<=1){ ps += __shfl_xor(ps, d); pd += __shfl_xor(pd, d); }
    if (n < N){
      union { _Float16 f; unsigned short u; } cv; cv.f = (_Float16)v;
      xlh[(size_t)n*128 + (ch&63)*2 + (ch>>6)] = cv.u;
      if ((ch & 31) == 0){ a_src[n*4 + h] = ps; a_dst[n*4 + h] = pd; }
    }
  }
}

// ---------------- edge_attr mean ----------------
__global__ void kEa(const float* __restrict__ ea, float* __restrict__ acc, int E){
  int gid = blockIdx.x*blockDim.x + threadIdx.x;
  float s = 0.f;
  for (int i = gid; i < E; i += gridDim.x*blockDim.x) s += ea[i];
  #pragma unroll
  for (int d=1; d<64; d<<=1) s += __shfl_xor(s, d);
  if ((threadIdx.x & 63) == 0) atomicAdd(acc, s);
}

// ---------------- CSR build (edge_index is int32 per harness spec) ----------------
__global__ void kDeg(const int* __restrict__ dst, int* __restrict__ deg, int E, int N){
  int e = blockIdx.x*256 + threadIdx.x;
  if (e < E){
    unsigned d = (unsigned)dst[e];
    if (d < (unsigned)N) atomicAdd(&deg[d], 1);
  }
}

__global__ __launch_bounds__(1024) void kScan(const int* __restrict__ deg, int* __restrict__ ptrA,
                                              int* __restrict__ cursor, int N){
  __shared__ int sWS[16];
  __shared__ int sWO[16];
  const int tid = threadIdx.x;
  const int C = (N + 1 + 1023) / 1024;
  const int i0 = tid * C;
  int local = 0;
  for (int i = i0; i < i0 + C && i < N; i++) local += deg[i];
  int lane = tid & 63, wv = tid >> 6;
  int v = local;
  #pragma unroll
  for (int d=1; d<64; d<<=1){ int u = __shfl_up(v, d); if (lane >= d) v += u; }
  if (lane == 63) sWS[wv] = v;
  __syncthreads();
  if (tid < 16){
    int s = sWS[tid];
    int vv = s;
    #pragma unroll
    for (int d=1; d<16; d<<=1){ int u = __shfl_up(vv, d); if (tid >= d) vv += u; }
    sWO[tid] = vv - s;
  }
  __syncthreads();
  int run = sWO[wv] + (v - local);
  for (int i = i0; i < i0 + C; i++){
    if (i <= N){
      ptrA[i] = run;
      if (i < N){ cursor[i] = run; run += deg[i]; }
    }
  }
}

__global__ void kFill(const int* __restrict__ dst, int* __restrict__ cursor,
                      int* __restrict__ csr, int E, int N){
  int e = blockIdx.x*256 + threadIdx.x;
  if (e < E){
    unsigned d = (unsigned)dst[e];
    if (d < (unsigned)N){ int p = atomicAdd(&cursor[d], 1); csr[p] = e; }
  }
}

// ---------------- GAT aggregation + elu + fc + relu ----------------
// xl gathered as ONE u32/lane/edge (fp16 pair: lo=ch lane, hi=ch lane+64)
__global__ __launch_bounds__(256) void kAgg(const unsigned short* __restrict__ xlh,
    const float* __restrict__ a_src,
    const float* __restrict__ a_dst, const int* __restrict__ esrc, const float* __restrict__ eattr,
    const int* __restrict__ ptrA, const int* __restrict__ csr, const float* __restrict__ cE,
    const float* __restrict__ eacc, const float* __restrict__ gat_bias, const float* __restrict__ fc_w,
    const float* __restrict__ fc_b, float* __restrict__ out, int N, int E)
{
  const int n = blockIdx.x*4 + (threadIdx.x >> 6);
  const int lane = threadIdx.x & 63;
  if (n >= N) return;
  const unsigned* xlp = (const unsigned*)xlh;
  float4 cEv = *(const float4*)cE;
  float eam = eacc[0] / (float)E;
  float4 ad  = *(const float4*)&a_dst[n*4];
  float4 asn = *(const float4*)&a_src[n*4];
  float sl0 = lrelu(asn.x + ad.x + eam*cEv.x);
  float sl1 = lrelu(asn.y + ad.y + eam*cEv.y);
  float sl2 = lrelu(asn.z + ad.z + eam*cEv.z);
  float sl3 = lrelu(asn.w + ad.w + eam*cEv.w);
  float mx0=sl0, mx1=sl1, mx2=sl2, mx3=sl3;
  const int p0 = ptrA[n], p1 = ptrA[n+1];
  for (int i = p0 + lane; i < p1; i += 64){
    int e = csr[i];
    int s = esrc[e];
    float ev = eattr[e];
    float4 av = *(const float4*)&a_src[s*4];
    mx0 = fmaxf(mx0, lrelu(av.x + ad.x + ev*cEv.x));
    mx1 = fmaxf(mx1, lrelu(av.y + ad.y + ev*cEv.y));
    mx2 = fmaxf(mx2, lrelu(av.z + ad.z + ev*cEv.z));
    mx3 = fmaxf(mx3, lrelu(av.w + ad.w + ev*cEv.w));
  }
  #pragma unroll
  for (int d=1; d<64; d<<=1){
    mx0 = fmaxf(mx0, __shfl_xor(mx0,d));
    mx1 = fmaxf(mx1, __shfl_xor(mx1,d));
    mx2 = fmaxf(mx2, __shfl_xor(mx2,d));
    mx3 = fmaxf(mx3, __shfl_xor(mx3,d));
  }
  const int ch0 = lane, ch1 = lane + 64;
  const int h0 = lane >> 5;
  float adh0 = h0 ? ad.y : ad.x,  adh1 = h0 ? ad.w : ad.z;
  float ceh0 = h0 ? cEv.y : cEv.x, ceh1 = h0 ? cEv.w : cEv.z;
  float mxh0 = h0 ? mx1 : mx0,    mxh1 = h0 ? mx3 : mx2;
  float slh0 = h0 ? sl1 : sl0,    slh1 = h0 ? sl3 : sl2;
  float pse0 = __expf(slh0 - mxh0), pse1 = __expf(slh1 - mxh1);
  float den0 = pse0, den1 = pse1;
  unsigned un = xlp[(size_t)n*64 + lane];
  float acc0 = pse0 * h2f_lo(un);
  float acc1 = pse1 * h2f_hi(un);
  for (int i = p0; i < p1; i++){
    int e = csr[i];
    int s = esrc[e];
    float ev = eattr[e];
    float4 av = *(const float4*)&a_src[s*4];
    float avh0 = h0 ? av.y : av.x;
    float avh1 = h0 ? av.w : av.z;
    float pp0 = __expf(lrelu(avh0 + adh0 + ev*ceh0) - mxh0);
    float pp1 = __expf(lrelu(avh1 + adh1 + ev*ceh1) - mxh1);
    den0 += pp0; den1 += pp1;
    unsigned u = xlp[(size_t)s*64 + lane];
    acc0 += pp0 * h2f_lo(u);
    acc1 += pp1 * h2f_hi(u);
  }
  float v0 = acc0/(den0 + 1e-16f) + gat_bias[ch0];
  float v1 = acc1/(den1 + 1e-16f) + gat_bias[ch1];
  v0 = v0 > 0.f ? v0 : __expf(v0) - 1.f;
  v1 = v1 > 0.f ? v1 : __expf(v1) - 1.f;
  #pragma unroll
  for (int o=0;o<4;o++){
    float p = fc_w[o*128 + ch0]*v0 + fc_w[o*128 + ch1]*v1;
    #pragma unroll
    for (int d=1; d<64; d<<=1) p += __shfl_xor(p, d);
    if (lane == 0) out[(size_t)n*4 + o] = fmaxf(p + fc_b[o], 0.f);
  }
}

extern "C" void kernel_launch(void* const* d_in, const int* in_sizes, int n_in,
                              void* d_out, int out_size, void* d_ws, size_t ws_size,
                              hipStream_t stream)
{
  (void)n_in; (void)out_size; (void)ws_size;
  const float* x          = (const float*)d_in[0];
  const int*   eidx       = (const int*)d_in[1];
  const float* eattr      = (const float*)d_in[2];
  const float* w_ih0      = (const float*)d_in[3];
  const float* w_hh0      = (const float*)d_in[4];
  const float* b_ih0      = (const float*)d_in[5];
  const float* b_hh0      = (const float*)d_in[6];
  const float* w_ih1      = (const float*)d_in[7];
  const float* w_hh1      = (const float*)d_in[8];
  const float* b_ih1      = (const float*)d_in[9];
  const float* b_hh1      = (const float*)d_in[10];
  const float* lin_w      = (const float*)d_in[11];
  const float* lin_edge_w = (const float*)d_in[12];
  const float* att_src    = (const float*)d_in[13];
  const float* att_dst    = (const float*)d_in[14];
  const float* att_edge   = (const float*)d_in[15];
  const float* gat_bias   = (const float*)d_in[16];
  const float* fc_w       = (const float*)d_in[17];
  const float* fc_b       = (const float*)d_in[18];
  float* out = (float*)d_out;

  const int N = in_sizes[0] / 32;
  const int E = in_sizes[1] / 2;
  const int* esrc = eidx;
  const int* edst = eidx + E;

  float* ws = (float*)d_ws;
  size_t o = 0;
  unsigned short* Bfrag = (unsigned short*)(ws + o); o += 24576;   // 49152 fp16
  float* linwT  = ws + o; o += 72*128;
  float* cE     = ws + o; o += 4;
  float* eacc   = ws + o; o += 4;
  float* h2last = ws + o; o += (size_t)N*64;
  unsigned short* xlh = (unsigned short*)(ws + o); o += (size_t)N*64;  // N*128 fp16
  float* a_src  = ws + o; o += (size_t)N*4;
  float* a_dst  = ws + o; o += (size_t)N*4;
  int* deg      = (int*)(ws + o); o += (size_t)N;
  int* ptrA     = (int*)(ws + o); o += (size_t)N + 1;
  int* cursor   = (int*)(ws + o); o += (size_t)N;
  int* csr      = (int*)(ws + o); o += (size_t)E;

  hipMemsetAsync(deg, 0, (size_t)N*4, stream);
  hipMemsetAsync(eacc, 0, 4, stream);
  kPrep<<<229, 256, 0, stream>>>(w_hh0, w_ih1, w_hh1, lin_w, lin_edge_w, att_edge,
                                 Bfrag, linwT, cE);
  kEa<<<512, 256, 0, stream>>>(eattr, eacc, E);
  kDeg<<<(E+255)/256, 256, 0, stream>>>(edst, deg, E, N);
  kScan<<<1, 1024, 0, stream>>>(deg, ptrA, cursor, N);
  kFill<<<(E+255)/256, 256, 0, stream>>>(edst, cursor, csr, E, N);

  kAB<<<(N+31)/32, 256, 0, stream>>>(x, Bfrag, w_ih0, b_ih0, b_hh0,
                                     b_ih1, b_hh1, h2last, N);

  kXL<<<(N+15)/16, 256, 0, stream>>>(h2last, x, linwT, att_src, att_dst, xlh, a_src, a_dst, N);
  kAgg<<<(N+3)/4, 256, 0, stream>>>(xlh, a_src, a_dst, esrc, eattr, ptrA, csr, cE, eacc,
                                    gat_bias, fc_w, fc_b, out, N, E);
}

// Round 13
// 837.058 us; speedup vs baseline: 1.0343x; 1.0343x over previous
//
#include <hip/hip_runtime.h>
#include <cstdint>

#define TT 24

typedef _Float16 half8 __attribute__((ext_vector_type(8)));
typedef float f32x4 __attribute__((ext_vector_type(4)));

static __device__ __forceinline__ float fsig(float x){
  float e = __builtin_amdgcn_exp2f(-1.44269504f*x);
  return __builtin_amdgcn_rcpf(1.0f + e);
}
static __device__ __forceinline__ float ftanh(float x){
  float e = __builtin_amdgcn_exp2f(-2.88539008f*x);
  return fmaf(2.0f, __builtin_amdgcn_rcpf(1.0f + e), -1.0f);
}
static __device__ __forceinline__ float lrelu(float x){ return x > 0.f ? x : 0.2f*x; }

static __device__ __forceinline__ int swzh(int b){ return b ^ (((b>>7)&7)<<4); }
static __device__ __forceinline__ float h2f_lo(unsigned u){
  union { unsigned short s; _Float16 f; } c; c.s = (unsigned short)(u & 0xFFFF); return (float)c.f;
}
static __device__ __forceinline__ float h2f_hi(unsigned u){
  union { unsigned short s; _Float16 f; } c; c.s = (unsigned short)(u >> 16); return (float)c.f;
}

// ---------------- prep: B-fragment build (fp16) + linwT + cE ----------------
// Bf[((mat*32 + c*16 + tau)*512) + l*8 + j] = fp16( W[k=32c+8*(l>>4)+j][col=16*tau+(l&15)] )
// where W[k][col] = wsrc[col*64+k]; mat 0=w_hh0, 1=w_ih1, 2=w_hh1. col = gate*64+jp.
__global__ void kPrep(const float* __restrict__ w_hh0, const float* __restrict__ w_ih1,
                      const float* __restrict__ w_hh1, const float* __restrict__ lin_w,
                      const float* __restrict__ lin_edge_w, const float* __restrict__ att_edge,
                      unsigned short* __restrict__ Bf,
                      float* __restrict__ linwT, float* __restrict__ cE)
{
  int gid = blockIdx.x*256 + threadIdx.x;
  if (gid < 49152){
    int mat = gid / 16384;
    int r = gid - mat*16384;
    int c = r>>13, nt = (r>>9)&15, l = (r>>3)&63, j = r&7;
    int k = c*32 + (l>>4)*8 + j;
    int col = nt*16 + (l&15);
    const float* wsrc = (mat==0) ? w_hh0 : (mat==1 ? w_ih1 : w_hh1);
    float v = wsrc[col*64 + k];
    union { _Float16 f; unsigned short u; } cv;
    cv.f = (_Float16)v;
    Bf[gid] = cv.u;
  }
  int g2 = gid - 49152;
  if (g2 >= 0 && g2 < 72*128){
    int k = g2 >> 7, ch = g2 & 127;
    linwT[g2] = lin_w[ch*72 + k];
  }
  if (gid >= 58368 && gid < 58372){
    int h = gid - 58368;
    float s = 0.f;
    for (int c=0;c<32;c++) s += lin_edge_w[h*32+c]*att_edge[h*32+c];
    cE[h] = s;
  }
}

// ---------------- fused 2-layer LSTM: fp16 MFMA, weights in VGPRs, 2 tiles/block ----------------
// 512 threads = 8 waves = 2 independent 32-node tiles (tile = wid>>2, wq = wid&3).
// 2 waves/SIMD guaranteed resident (VGPR ~140 < 256) -> intra-phase latency hiding
// (R11 lesson: 4-wave blocks left 1 wave/SIMD, latency fully exposed).
// h state double-buffered (read cur, write nxt) -> 2 barriers/step instead of 3:
//   Bmid: h1(t) cross-wave visibility before GEMM1; Bend: h2(t) before next GEMM0.
//   WAR hazards eliminated by buffer split (writes never touch the buffer being read).
// Weights preloaded to VGPR per wave (24 x half8 = 96 VGPR), zero weight reads in loop.
// A/B k-slot convention (verified R6-R11): k = c*32 + (lane>>4)*8 + j both operands.
// C/D: col=lane&15, row=(lane>>4)*4+reg (m89).
__global__ __launch_bounds__(512) void kAB(const float* __restrict__ x,
    const unsigned short* __restrict__ Bf,
    const float* __restrict__ w_ih0, const float* __restrict__ b_ih0, const float* __restrict__ b_hh0,
    const float* __restrict__ b_ih1, const float* __restrict__ b_hh1,
    float* __restrict__ h2last, int N)
{
  __shared__ __align__(16) unsigned short sH1[2][2][2048];  // [tile][buf][32 node x 64 jp]
  __shared__ __align__(16) unsigned short sH2[2][2][2048];
  __shared__ float sX[2][800];                              // [tile][32 node x stride25]
  const int tid = threadIdx.x;
  const int wid = tid>>6, l = tid&63;
  const int tile = wid>>2, wq = wid&3;
  const int lr = l&15, lg = l>>4;
  const int nb = blockIdx.x*64 + tile*32;

  for (int i=tid;i<1600;i+=512){
    int tl = i/800, r = i - tl*800;
    int m = r/25, tt = r - m*25;
    if (tt < 24){
      int n = blockIdx.x*64 + tl*32 + m;
      sX[tl][m*25+tt] = (n<N) ? x[(size_t)n*32 + 8 + tt] : 0.f;
    }
  }
  {
    unsigned short* f1 = &sH1[0][0][0];
    unsigned short* f2 = &sH2[0][0][0];
    for (int i=tid;i<8192;i+=512){ f1[i]=0; f2[i]=0; }
  }

  // per-wave weight fragments -> VGPR (compile-time indexed after unroll)
  half8 w0[2][4], w1i[2][4], w1h[2][4];
  #pragma unroll
  for (int c=0;c<2;c++){
    #pragma unroll
    for (int nt=0;nt<4;nt++){
      w0 [c][nt] = *(const half8*)&Bf[(( 0 + c*16 + nt*4 + wq)<<9) + l*8];
      w1i[c][nt] = *(const half8*)&Bf[((32 + c*16 + nt*4 + wq)<<9) + l*8];
      w1h[c][nt] = *(const half8*)&Bf[((64 + c*16 + nt*4 + wq)<<9) + l*8];
    }
  }

  float wih[4], bb0[4], bb1[4];
  #pragma unroll
  for (int nt=0;nt<4;nt++){
    int col = nt*64 + wq*16 + lr;
    wih[nt] = w_ih0[col];
    bb0[nt] = b_ih0[col] + b_hh0[col];
    bb1[nt] = b_ih1[col] + b_hh1[col];
  }
  float cc0[8], cc1[8];
  #pragma unroll
  for (int i=0;i<8;i++){ cc0[i]=0.f; cc1[i]=0.f; }
  __syncthreads();

  for (int t=0;t<TT;t++){
    const int cur = t&1, nxt = cur^1;
    const char* h1c = (const char*)sH1[tile][cur];
    const char* h2c = (const char*)sH2[tile][cur];
    char* h1n = (char*)sH1[tile][nxt];
    char* h2n = (char*)sH2[tile][nxt];

    // ========== GEMM0: preact0 = h1(t-1)*W0 + x_t*wih + b  (acc in regs) ==========
    f32x4 acc[2][4];
    #pragma unroll
    for (int mt=0;mt<2;mt++){
      #pragma unroll
      for (int r=0;r<4;r++){
        float xv = sX[tile][(mt*16 + lg*4 + r)*25 + t];
        #pragma unroll
        for (int nt=0;nt<4;nt++) acc[mt][nt][r] = fmaf(xv, wih[nt], bb0[nt]);
      }
    }
    #pragma unroll
    for (int c=0;c<2;c++){
      half8 a[2];
      #pragma unroll
      for (int mt=0;mt<2;mt++)
        a[mt] = *(const half8*)(h1c + swzh((mt*16+lr)*128 + c*64 + lg*16));
      #pragma unroll
      for (int nt=0;nt<4;nt++){
        #pragma unroll
        for (int mt=0;mt<2;mt++)
          acc[mt][nt] = __builtin_amdgcn_mfma_f32_16x16x32_f16(a[mt], w0[c][nt], acc[mt][nt], 0,0,0);
      }
    }
    // ========== nonlin0 (registers) -> write h1(t) to NXT buffer ==========
    #pragma unroll
    for (int mt=0;mt<2;mt++){
      #pragma unroll
      for (int r=0;r<4;r++){
        int idx = mt*4+r, nd = mt*16 + lg*4 + r;
        float ig = fsig(acc[mt][0][r]), fg = fsig(acc[mt][1][r]);
        float gg = ftanh(acc[mt][2][r]), og = fsig(acc[mt][3][r]);
        cc0[idx] = fg*cc0[idx] + ig*gg;
        float h = og*ftanh(cc0[idx]);
        union { _Float16 f; unsigned short u; } cv; cv.f = (_Float16)h;
        *(unsigned short*)(h1n + swzh(nd*128 + (wq*16+lr)*2)) = cv.u;
      }
    }
    __syncthreads();   // Bmid: h1(t) visible to all waves of this tile
    // ========== GEMM1: preact1 = [h1(t);h2(t-1)] * [Wih1;Whh1] + b ==========
    #pragma unroll
    for (int mt=0;mt<2;mt++)
      #pragma unroll
      for (int nt=0;nt<4;nt++)
        #pragma unroll
        for (int r=0;r<4;r++) acc[mt][nt][r] = bb1[nt];
    #pragma unroll
    for (int c4=0;c4<4;c4++){
      const char* srcA = (c4<2) ? (const char*)h1n : h2c;
      const int cc = c4&1;
      half8 a[2];
      #pragma unroll
      for (int mt=0;mt<2;mt++)
        a[mt] = *(const half8*)(srcA + swzh((mt*16+lr)*128 + cc*64 + lg*16));
      #pragma unroll
      for (int nt=0;nt<4;nt++){
        half8 b = (c4<2) ? w1i[cc][nt] : w1h[cc][nt];
        #pragma unroll
        for (int mt=0;mt<2;mt++)
          acc[mt][nt] = __builtin_amdgcn_mfma_f32_16x16x32_f16(a[mt], b, acc[mt][nt], 0,0,0);
      }
    }
    // ========== nonlin1 (registers) -> write h2(t) to NXT buffer; fp32 out at t=23 ==========
    #pragma unroll
    for (int mt=0;mt<2;mt++){
      #pragma unroll
      for (int r=0;r<4;r++){
        int idx = mt*4+r, nd = mt*16 + lg*4 + r;
        float ig = fsig(acc[mt][0][r]), fg = fsig(acc[mt][1][r]);
        float gg = ftanh(acc[mt][2][r]), og = fsig(acc[mt][3][r]);
        cc1[idx] = fg*cc1[idx] + ig*gg;
        float h = og*ftanh(cc1[idx]);
        union { _Float16 f; unsigned short u; } cv; cv.f = (_Float16)h;
        *(unsigned short*)(h2n + swzh(nd*128 + (wq*16+lr)*2)) = cv.u;
        if (t == TT-1){
          int n = nb + nd;
          if (n < N) h2last[(size_t)n*64 + wq*16 + lr] = h;
        }
      }
    }
    __syncthreads();   // Bend: h2(t) visible before GEMM0/GEMM1 of t+1
  }
}

// ---------------- GAT linear + attention coefficients ----------------
// xl stored PACKED fp16: ushort at n*128 + (ch&63)*2 + (ch>>6)  (pair = one u32/lane in kAgg)
__global__ __launch_bounds__(256) void kXL(const float* __restrict__ h2last, const float* __restrict__ x,
    const float* __restrict__ linwT, const float* __restrict__ att_src, const float* __restrict__ att_dst,
    unsigned short* __restrict__ xlh, float* __restrict__ a_src, float* __restrict__ a_dst, int N)
{
  __shared__ float sLW[72*128];
  __shared__ float sC[16*72];
  const int tid = threadIdx.x;
  const int nb0 = blockIdx.x * 16;
  for (int i = tid*4; i < 9216; i += 1024)
    *(float4*)&sLW[i] = *(const float4*)&linwT[i];
  for (int i = tid; i < 16*64; i += 256){
    int m = i >> 6, k = i & 63; int n = nb0 + m;
    sC[m*72 + k] = (n < N) ? h2last[(size_t)n*64 + k] : 0.f;
  }
  if (tid < 128){
    int m = tid >> 3, j = tid & 7; int n = nb0 + m;
    sC[m*72 + 64 + j] = (n < N) ? x[(size_t)n*32 + j] : 0.f;
  }
  __syncthreads();
  const int ch = tid & 127, half = tid >> 7;
  float acc[8];
  #pragma unroll
  for (int m=0;m<8;m++) acc[m]=0.f;
  for (int k=0;k<72;k++){
    float w = sLW[k*128 + ch];
    #pragma unroll
    for (int m=0;m<8;m++) acc[m] += w * sC[(half*8+m)*72 + k];
  }
  float aS = att_src[ch], aD = att_dst[ch];
  int h = ch >> 5;
  #pragma unroll
  for (int m=0;m<8;m++){
    int n = nb0 + half*8 + m;
    float v = acc[m];
    float ps = v*aS, pd = v*aD;
    #pragma unroll
    for (int d=1; d<32; d<<=1){ ps += __shfl_xor(ps, d); pd += __shfl_xor(pd, d); }
    if (n < N){
      union { _Float16 f; unsigned short u; } cv; cv.f = (_Float16)v;
      xlh[(size_t)n*128 + (ch&63)*2 + (ch>>6)] = cv.u;
      if ((ch & 31) == 0){ a_src[n*4 + h] = ps; a_dst[n*4 + h] = pd; }
    }
  }
}

// ---------------- edge_attr mean ----------------
__global__ void kEa(const float* __restrict__ ea, float* __restrict__ acc, int E){
  int gid = blockIdx.x*blockDim.x + threadIdx.x;
  float s = 0.f;
  for (int i = gid; i < E; i += gridDim.x*blockDim.x) s += ea[i];
  #pragma unroll
  for (int d=1; d<64; d<<=1) s += __shfl_xor(s, d);
  if ((threadIdx.x & 63) == 0) atomicAdd(acc, s);
}

// ---------------- CSR build (edge_index is int32 per harness spec) ----------------
__global__ void kDeg(const int* __restrict__ dst, int* __restrict__ deg, int E, int N){
  int e = blockIdx.x*256 + threadIdx.x;
  if (e < E){
    unsigned d = (unsigned)dst[e];
    if (d < (unsigned)N) atomicAdd(&deg[d], 1);
  }
}

__global__ __launch_bounds__(1024) void kScan(const int* __restrict__ deg, int* __restrict__ ptrA,
                                              int* __restrict__ cursor, int N){
  __shared__ int sWS[16];
  __shared__ int sWO[16];
  const int tid = threadIdx.x;
  const int C = (N + 1 + 1023) / 1024;
  const int i0 = tid * C;
  int local = 0;
  for (int i = i0; i < i0 + C && i < N; i++) local += deg[i];
  int lane = tid & 63, wv = tid >> 6;
  int v = local;
  #pragma unroll
  for (int d=1; d<64; d<<=1){ int u = __shfl_up(v, d); if (lane >= d) v += u; }
  if (lane == 63) sWS[wv] = v;
  __syncthreads();
  if (tid < 16){
    int s = sWS[tid];
    int vv = s;
    #pragma unroll
    for (int d=1; d<16; d<<=1){ int u = __shfl_up(vv, d); if (tid >= d) vv += u; }
    sWO[tid] = vv - s;
  }
  __syncthreads();
  int run = sWO[wv] + (v - local);
  for (int i = i0; i < i0 + C; i++){
    if (i <= N){
      ptrA[i] = run;
      if (i < N){ cursor[i] = run; run += deg[i]; }
    }
  }
}

__global__ void kFill(const int* __restrict__ dst, int* __restrict__ cursor,
                      int* __restrict__ csr, int E, int N){
  int e = blockIdx.x*256 + threadIdx.x;
  if (e < E){
    unsigned d = (unsigned)dst[e];
    if (d < (unsigned)N){ int p = atomicAdd(&cursor[d], 1); csr[p] = e; }
  }
}

// ---------------- GAT aggregation + elu + fc + relu ----------------
// xl gathered as ONE u32/lane/edge (fp16 pair: lo=ch lane, hi=ch lane+64)
__global__ __launch_bounds__(256) void kAgg(const unsigned short* __restrict__ xlh,
    const float* __restrict__ a_src,
    const float* __restrict__ a_dst, const int* __restrict__ esrc, const float* __restrict__ eattr,
    const int* __restrict__ ptrA, const int* __restrict__ csr, const float* __restrict__ cE,
    const float* __restrict__ eacc, const float* __restrict__ gat_bias, const float* __restrict__ fc_w,
    const float* __restrict__ fc_b, float* __restrict__ out, int N, int E)
{
  const int n = blockIdx.x*4 + (threadIdx.x >> 6);
  const int lane = threadIdx.x & 63;
  if (n >= N) return;
  const unsigned* xlp = (const unsigned*)xlh;
  float4 cEv = *(const float4*)cE;
  float eam = eacc[0] / (float)E;
  float4 ad  = *(const float4*)&a_dst[n*4];
  float4 asn = *(const float4*)&a_src[n*4];
  float sl0 = lrelu(asn.x + ad.x + eam*cEv.x);
  float sl1 = lrelu(asn.y + ad.y + eam*cEv.y);
  float sl2 = lrelu(asn.z + ad.z + eam*cEv.z);
  float sl3 = lrelu(asn.w + ad.w + eam*cEv.w);
  float mx0=sl0, mx1=sl1, mx2=sl2, mx3=sl3;
  const int p0 = ptrA[n], p1 = ptrA[n+1];
  for (int i = p0 + lane; i < p1; i += 64){
    int e = csr[i];
    int s = esrc[e];
    float ev = eattr[e];
    float4 av = *(const float4*)&a_src[s*4];
    mx0 = fmaxf(mx0, lrelu(av.x + ad.x + ev*cEv.x));
    mx1 = fmaxf(mx1, lrelu(av.y + ad.y + ev*cEv.y));
    mx2 = fmaxf(mx2, lrelu(av.z + ad.z + ev*cEv.z));
    mx3 = fmaxf(mx3, lrelu(av.w + ad.w + ev*cEv.w));
  }
  #pragma unroll
  for (int d=1; d<64; d<<=1){
    mx0 = fmaxf(mx0, __shfl_xor(mx0,d));
    mx1 = fmaxf(mx1, __shfl_xor(mx1,d));
    mx2 = fmaxf(mx2, __shfl_xor(mx2,d));
    mx3 = fmaxf(mx3, __shfl_xor(mx3,d));
  }
  const int ch0 = lane, ch1 = lane + 64;
  const int h0 = lane >> 5;
  float adh0 = h0 ? ad.y : ad.x,  adh1 = h0 ? ad.w : ad.z;
  float ceh0 = h0 ? cEv.y : cEv.x, ceh1 = h0 ? cEv.w : cEv.z;
  float mxh0 = h0 ? mx1 : mx0,    mxh1 = h0 ? mx3 : mx2;
  float slh0 = h0 ? sl1 : sl0,    slh1 = h0 ? sl3 : sl2;
  float pse0 = __expf(slh0 - mxh0), pse1 = __expf(slh1 - mxh1);
  float den0 = pse0, den1 = pse1;
  unsigned un = xlp[(size_t)n*64 + lane];
  float acc0 = pse0 * h2f_lo(un);
  float acc1 = pse1 * h2f_hi(un);
  for (int i = p0; i < p1; i++){
    int e = csr[i];
    int s = esrc[e];
    float ev = eattr[e];
    float4 av = *(const float4*)&a_src[s*4];
    float avh0 = h0 ? av.y : av.x;
    float avh1 = h0 ? av.w : av.z;
    float pp0 = __expf(lrelu(avh0 + adh0 + ev*ceh0) - mxh0);
    float pp1 = __expf(lrelu(avh1 + adh1 + ev*ceh1) - mxh1);
    den0 += pp0; den1 += pp1;
    unsigned u = xlp[(size_t)s*64 + lane];
    acc0 += pp0 * h2f_lo(u);
    acc1 += pp1 * h2f_hi(u);
  }
  float v0 = acc0/(den0 + 1e-16f) + gat_bias[ch0];
  float v1 = acc1/(den1 + 1e-16f) + gat_bias[ch1];
  v0 = v0 > 0.f ? v0 : __expf(v0) - 1.f;
  v1 = v1 > 0.f ? v1 : __expf(v1) - 1.f;
  #pragma unroll
  for (int o=0;o<4;o++){
    float p = fc_w[o*128 + ch0]*v0 + fc_w[o*128 + ch1]*v1;
    #pragma unroll
    for (int d=1; d<64; d<<=1) p += __shfl_xor(p, d);
    if (lane == 0) out[(size_t)n*4 + o] = fmaxf(p + fc_b[o], 0.f);
  }
}

extern "C" void kernel_launch(void* const* d_in, const int* in_sizes, int n_in,
                              void* d_out, int out_size, void* d_ws, size_t ws_size,
                              hipStream_t stream)
{
  (void)n_in; (void)out_size; (void)ws_size;
  const float* x          = (const float*)d_in[0];
  const int*   eidx       = (const int*)d_in[1];
  const float* eattr      = (const float*)d_in[2];
  const float* w_ih0      = (const float*)d_in[3];
  const float* w_hh0      = (const float*)d_in[4];
  const float* b_ih0      = (const float*)d_in[5];
  const float* b_hh0      = (const float*)d_in[6];
  const float* w_ih1      = (const float*)d_in[7];
  const float* w_hh1      = (const float*)d_in[8];
  const float* b_ih1      = (const float*)d_in[9];
  const float* b_hh1      = (const float*)d_in[10];
  const float* lin_w      = (const float*)d_in[11];
  const float* lin_edge_w = (const float*)d_in[12];
  const float* att_src    = (const float*)d_in[13];
  const float* att_dst    = (const float*)d_in[14];
  const float* att_edge   = (const float*)d_in[15];
  const float* gat_bias   = (const float*)d_in[16];
  const float* fc_w       = (const float*)d_in[17];
  const float* fc_b       = (const float*)d_in[18];
  float* out = (float*)d_out;

  const int N = in_sizes[0] / 32;
  const int E = in_sizes[1] / 2;
  const int* esrc = eidx;
  const int* edst = eidx + E;

  float* ws = (float*)d_ws;
  size_t o = 0;
  unsigned short* Bfrag = (unsigned short*)(ws + o); o += 24576;   // 49152 fp16
  float* linwT  = ws + o; o += 72*128;
  float* cE     = ws + o; o += 4;
  float* eacc   = ws + o; o += 4;
  float* h2last = ws + o; o += (size_t)N*64;
  unsigned short* xlh = (unsigned short*)(ws + o); o += (size_t)N*64;  // N*128 fp16
  float* a_src  = ws + o; o += (size_t)N*4;
  float* a_dst  = ws + o; o += (size_t)N*4;
  int* deg      = (int*)(ws + o); o += (size_t)N;
  int* ptrA     = (int*)(ws + o); o += (size_t)N + 1;
  int* cursor   = (int*)(ws + o); o += (size_t)N;
  int* csr      = (int*)(ws + o); o += (size_t)E;

  hipMemsetAsync(deg, 0, (size_t)N*4, stream);
  hipMemsetAsync(eacc, 0, 4, stream);
  kPrep<<<229, 256, 0, stream>>>(w_hh0, w_ih1, w_hh1, lin_w, lin_edge_w, att_edge,
                                 Bfrag, linwT, cE);
  kEa<<<512, 256, 0, stream>>>(eattr, eacc, E);
  kDeg<<<(E+255)/256, 256, 0, stream>>>(edst, deg, E, N);
  kScan<<<1, 1024, 0, stream>>>(deg, ptrA, cursor, N);
  kFill<<<(E+255)/256, 256, 0, stream>>>(edst, cursor, csr, E, N);

  kAB<<<(N+63)/64, 512, 0, stream>>>(x, Bfrag, w_ih0, b_ih0, b_hh0,
                                     b_ih1, b_hh1, h2last, N);

  kXL<<<(N+15)/16, 256, 0, stream>>>(h2last, x, linwT, att_src, att_dst, xlh, a_src, a_dst, N);
  kAgg<<<(N+3)/4, 256, 0, stream>>>(xlh, a_src, a_dst, esrc, eattr, ptrA, csr, cE, eacc,
                                    gat_bias, fc_w, fc_b, out, N, E);
}